// Round 1
// baseline (1027.616 us; speedup 1.0000x reference)
//
#include <hip/hip_runtime.h>
#include <hip/hip_bf16.h>

// ---- problem constants ----
#define BB_   16
#define QQ_   1024
#define CC_   1280
#define LFULL 477
#define CROSS 2048
#define NTOK  200
#define HEADS 20
#define HD    64
#define EHSL  77      // 477 - 200 - 200
#define SCALE_ 0.125f  // 1/sqrt(64)

typedef short bf16x8 __attribute__((ext_vector_type(8)));
typedef float f32x4  __attribute__((ext_vector_type(4)));

__device__ __forceinline__ unsigned short f2bf(float f){
    unsigned u = __float_as_uint(f);
    return (unsigned short)((u + 0x7fffu + ((u >> 16) & 1u)) >> 16);
}
__device__ __forceinline__ unsigned pack2(float a, float b){
    return (unsigned)f2bf(a) | ((unsigned)f2bf(b) << 16);
}
__device__ __forceinline__ float bfu(unsigned short u){
    return __uint_as_float(((unsigned)u) << 16);
}

__device__ __forceinline__ void store_out(unsigned short* p, float v){ *p = f2bf(v); }
__device__ __forceinline__ void store_out(float* p, float v){ *p = v; }

// async global->LDS 16B copy (dest = wave-uniform base + lane*16)
typedef __attribute__((address_space(3))) char lds_char_t;
typedef __attribute__((address_space(1))) char glb_char_t;
__device__ __forceinline__ void async16(const void* g, void* l){
    __builtin_amdgcn_global_load_lds((const glb_char_t*)g, (lds_char_t*)l, 16, 0, 0);
}

// ============================================================================
// 128x128-tile GEMM, 2-phase depth-1 pipeline (catalog T3 minimal recipe):
// double-buffered LDS; each iter ISSUES next tile's global_load_lds first,
// then computes current tile from LDS, then s_waitcnt vmcnt(0) + raw
// s_barrier (NOT __syncthreads, which would drain the prefetch).
// T1: bijective XCD block remap (m204) so the gridDim.x blocks sharing an
// A-stripe co-reside on one XCD's L2.
// C[m][n] = sum_k A[m][k]*W[n][k] (+bias); A,W bf16 row-major K-inner.
// 256 threads = 4 waves, each 64x64 via 4x4 mfma_f32_16x16x32_bf16, BK=64.
// A-row mapping phys = (m/rpb)*bstride + m%rpb handles the encoder slices.
// Race audit: staging into buf[cur^1] at iter t races only with iter t-1
// reads of that buffer; those ds_reads are consumed by MFMAs before the
// end-of-(t-1) barrier (asm waitcnt is a sched boundary; sched_barrier(0)
// pins MFMAs from sinking past it). Staging predicate is block-uniform.
// ============================================================================
template<typename OT>
__global__ __launch_bounds__(256) void gemm128(
    const unsigned short* __restrict__ A,
    const unsigned short* __restrict__ W,
    const float* __restrict__ bias,
    OT* __restrict__ C,
    int M, int N, int K, int rpb, int bstride)
{
    __shared__ unsigned short sA[2][8192];   // 2 x 16 KB
    __shared__ unsigned short sB[2][8192];

    const int tid  = threadIdx.x;
    const int lane = tid & 63;
    const int wave = tid >> 6;
    const int quad = lane >> 4;
    const int l16  = lane & 15;
    const int wm   = wave >> 1;
    const int wn   = wave & 1;

    // T1: XCD-aware bijective remap (m204 formula; safe for nwg % 8 != 0)
    int flat = blockIdx.y * gridDim.x + blockIdx.x;
    {
        const int nwg = (int)(gridDim.x * gridDim.y);
        const int q = nwg >> 3, r = nwg & 7;
        const int xcd = flat & 7, idx = flat >> 3;
        flat = (xcd < r ? xcd * (q + 1) : r * (q + 1) + (xcd - r) * q) + idx;
    }
    const int tm = (flat / (int)gridDim.x) * 128;
    const int tn = (flat % (int)gridDim.x) * 128;

    const unsigned short* pA[4];
    const unsigned short* pB[4];
    #pragma unroll
    for (int r = 0; r < 4; r++){
        int t = r * 256 + tid;
        int kg = t >> 7, row = t & 127;
        int gm = tm + row; if (gm > M - 1) gm = M - 1;
        int bb = gm / rpb, rr = gm - bb * rpb;
        pA[r] = A + ((size_t)bb * bstride + rr) * (size_t)K + kg * 8;
        pB[r] = W + (size_t)(tn + row) * K + kg * 8;
    }

    f32x4 acc[4][4];
    #pragma unroll
    for (int i = 0; i < 4; i++)
        #pragma unroll
        for (int j = 0; j < 4; j++)
            acc[i][j] = (f32x4){0.f, 0.f, 0.f, 0.f};

    // prologue: stage tile 0 into buffer 0, drain, barrier
    #pragma unroll
    for (int r = 0; r < 4; r++){
        async16(pA[r], (char*)&sA[0][0] + (r * 256 + wave * 64) * 16);
        async16(pB[r], (char*)&sB[0][0] + (r * 256 + wave * 64) * 16);
        pA[r] += 64;
        pB[r] += 64;
    }
    asm volatile("s_waitcnt vmcnt(0)" ::: "memory");
    __builtin_amdgcn_s_barrier();

    int cur = 0;
    for (int k0 = 0; k0 < K; k0 += 64){
        // issue next tile's loads FIRST (they stay in flight across compute)
        if (k0 + 64 < K){
            #pragma unroll
            for (int r = 0; r < 4; r++){
                async16(pA[r], (char*)&sA[cur ^ 1][0] + (r * 256 + wave * 64) * 16);
                async16(pB[r], (char*)&sB[cur ^ 1][0] + (r * 256 + wave * 64) * 16);
                pA[r] += 64;
                pB[r] += 64;
            }
        }

        const unsigned short* cA = &sA[cur][0];
        const unsigned short* cB = &sB[cur][0];
        #pragma unroll
        for (int ks = 0; ks < 2; ks++){
            bf16x8 af[4], bv[4];
            #pragma unroll
            for (int s = 0; s < 4; s++){
                af[s] = *(const bf16x8*)(cA + (((ks*4 + quad) * 128) + wm*64 + s*16 + l16) * 8);
                bv[s] = *(const bf16x8*)(cB + (((ks*4 + quad) * 128) + wn*64 + s*16 + l16) * 8);
            }
            #pragma unroll
            for (int i = 0; i < 4; i++)
                #pragma unroll
                for (int j = 0; j < 4; j++)
                    acc[i][j] = __builtin_amdgcn_mfma_f32_16x16x32_bf16(af[i], bv[j], acc[i][j], 0, 0, 0);
        }

        // pin compute before the barrier (don't let MFMAs/lgkm waits sink),
        // wait for next tile's loads, then raw barrier (no implicit drain)
        __builtin_amdgcn_sched_barrier(0);
        asm volatile("s_waitcnt vmcnt(0)" ::: "memory");
        __builtin_amdgcn_s_barrier();
        cur ^= 1;
    }

    #pragma unroll
    for (int i = 0; i < 4; i++){
        const int r0 = tm + wm*64 + i*16 + quad*4;
        #pragma unroll
        for (int j = 0; j < 4; j++){
            const int col = tn + wn*64 + j*16 + l16;
            const float bs = bias ? bias[col] : 0.f;
            #pragma unroll
            for (int r = 0; r < 4; r++){
                const int row = r0 + r;
                if (row < M) store_out(C + (size_t)row * N + col, acc[i][j][r] + bs);
            }
        }
    }
}

// ============================================================================
// MFMA flash attention. Block = 4 waves; each wave owns 16 q-rows (block: 64).
// Per (b,h): stage K (pitch 72) and V^T (pitch vp = nk32*32+8, both give
// 2-way-only bank aliasing) in LDS. Per k32 chunk:
//   S-tiles (2x): mfma(Q-frag, K-rows-as-B) -> C-layout S[q=quad*4+r][k=l16];
//   exp + (kpos<Lk) mask -> P bf16 to wave-private LDS (16x40, A-layout);
//   PV: A=P-frag, B=V^T rows (ds_read_b128); ones-column MFMA accumulates the
//   softmax denominator l for free (no max-subtract: scores are O(1), clamp 80).
// Epilogue: broadcast l from l16==0 lanes via ds_swizzle(0x10), scale, +Add,
// scalar bf16 stores. In-place safe: Q read before staging barrier; each block
// writes only its own q-rows.
// ============================================================================
__global__ __launch_bounds__(256) void mattn(
    const unsigned short* __restrict__ Q,  int qstride, int qcoff,
    const unsigned short* __restrict__ KV, int kvstride, int vcoff,
    const unsigned short* __restrict__ Add,              // may be null
    unsigned short* __restrict__ O,   int ostride, int ocoff,
    int qrows, int Lk)
{
    extern __shared__ __align__(16) unsigned short smem[];
    const int Lkc16 = (Lk + 15) & ~15;
    const int nk32  = (Lk + 31) >> 5;
    const int vp    = nk32 * 32 + 8;

    const int tid  = threadIdx.x;
    const int lane = tid & 63;
    const int wave = tid >> 6;
    const int quad = lane >> 4;
    const int l16  = lane & 15;

    unsigned short* sK  = smem;
    unsigned short* sVT = smem + Lkc16 * 72;
    unsigned short* sP  = sVT + 64 * vp + wave * 640;   // 16 x 40 per wave

    const int b = blockIdx.x / HEADS;
    const int h = blockIdx.x % HEADS;
    const int q0 = blockIdx.y * 64 + wave * 16;

    // Q fragments (A-operand: m=l16, k=quad*8+j), loaded before the barrier
    const int qr = min(q0 + l16, qrows - 1);
    const unsigned short* qp = Q + (size_t)(b * qrows + qr) * qstride + h * HD + qcoff;
    bf16x8 qa0 = *(const bf16x8*)(qp + quad * 8);
    bf16x8 qa1 = *(const bf16x8*)(qp + 32 + quad * 8);

    // stage K rows [0, Lkc16), source row clamped
    for (int t = tid; t < Lkc16 * 8; t += 256){
        int row = t >> 3, c = t & 7;
        int sr = min(row, Lk - 1);
        uint4 val = *(const uint4*)(KV + (size_t)(b * Lk + sr) * kvstride + h * HD + c * 8);
        *(uint4*)(sK + row * 72 + c * 8) = val;
    }
    // stage V transposed: V^T[d][kpos], kpos in [0, nk32*32)
    for (int t = tid; t < nk32 * 32 * 8; t += 256){
        int kp_ = t >> 3, c = t & 7;
        int sr = min(kp_, Lk - 1);
        uint4 val = *(const uint4*)(KV + (size_t)(b * Lk + sr) * kvstride + h * HD + vcoff + c * 8);
        unsigned short* col = sVT + (c * 8) * vp + kp_;
        col[0*vp] = (unsigned short)(val.x & 0xffff);
        col[1*vp] = (unsigned short)(val.x >> 16);
        col[2*vp] = (unsigned short)(val.y & 0xffff);
        col[3*vp] = (unsigned short)(val.y >> 16);
        col[4*vp] = (unsigned short)(val.z & 0xffff);
        col[5*vp] = (unsigned short)(val.z >> 16);
        col[6*vp] = (unsigned short)(val.w & 0xffff);
        col[7*vp] = (unsigned short)(val.w >> 16);
    }
    __syncthreads();

    // ones B-fragment: column n==0 of the l-tile
    union { unsigned short us[8]; bf16x8 v; } onesu;
    {
        unsigned short ov = (l16 == 0) ? (unsigned short)0x3f80 : (unsigned short)0;
        #pragma unroll
        for (int i = 0; i < 8; i++) onesu.us[i] = ov;
    }

    f32x4 oacc[4], lacc;
    #pragma unroll
    for (int i = 0; i < 4; i++) oacc[i] = (f32x4){0.f, 0.f, 0.f, 0.f};
    lacc = (f32x4){0.f, 0.f, 0.f, 0.f};

    for (int kb = 0; kb < nk32; kb++){
        #pragma unroll
        for (int st = 0; st < 2; st++){
            const int kt = kb * 32 + st * 16;
            const int krow = min(kt + l16, Lkc16 - 1);
            const unsigned short* kp = sK + krow * 72 + quad * 8;
            bf16x8 k0 = *(const bf16x8*)(kp);
            bf16x8 k1 = *(const bf16x8*)(kp + 32);
            f32x4 s = (f32x4){0.f, 0.f, 0.f, 0.f};
            s = __builtin_amdgcn_mfma_f32_16x16x32_bf16(qa0, k0, s, 0, 0, 0);
            s = __builtin_amdgcn_mfma_f32_16x16x32_bf16(qa1, k1, s, 0, 0, 0);
            const bool valid = (kt + l16) < Lk;
            #pragma unroll
            for (int r = 0; r < 4; r++){
                float sv = fminf(s[r] * SCALE_, 80.f);
                float w = valid ? __expf(sv) : 0.f;
                sP[(quad * 4 + r) * 40 + st * 16 + l16] = f2bf(w);
            }
        }
        // P fragment (A-operand) — wave-private buffer, lgkmcnt ordering only
        bf16x8 pf = *(const bf16x8*)(sP + l16 * 40 + quad * 8);
        lacc = __builtin_amdgcn_mfma_f32_16x16x32_bf16(pf, onesu.v, lacc, 0, 0, 0);
        #pragma unroll
        for (int dt = 0; dt < 4; dt++){
            bf16x8 vb = *(const bf16x8*)(sVT + (dt * 16 + l16) * vp + kb * 32 + quad * 8);
            oacc[dt] = __builtin_amdgcn_mfma_f32_16x16x32_bf16(pf, vb, oacc[dt], 0, 0, 0);
        }
    }

    // epilogue: broadcast l within each quad from l16==0, normalize, add, store
    #pragma unroll
    for (int r = 0; r < 4; r++){
        int li = __builtin_amdgcn_ds_swizzle(__float_as_int(lacc[r]), 0x0010);
        float inv = __builtin_amdgcn_rcpf(__int_as_float(li));
        const int qrow = q0 + quad * 4 + r;
        if (qrow < qrows){
            const size_t og = (size_t)(b * qrows + qrow) * ostride + h * HD + ocoff;
            #pragma unroll
            for (int dt = 0; dt < 4; dt++){
                float v = oacc[dt][r] * inv;
                if (Add) v += bfu(Add[og + dt * 16 + l16]);
                O[og + dt * 16 + l16] = f2bf(v);
            }
        }
    }
}

// ============================================================================
// fp32 -> bf16 conversion, 10 tensors fused (8 weights + hs + enc).
// ============================================================================
struct Cvt10 { const float* src[10]; unsigned short* dst[10]; };

__global__ __launch_bounds__(256) void cvt10_kernel(Cvt10 a)
{
    const unsigned counts[10] = {1638400u, 2621440u, 2621440u, 2621440u,
                                 2621440u, 2621440u, 2621440u, 1638400u,
                                 20971520u, 15630336u};
    size_t e = ((size_t)blockIdx.x * 256 + threadIdx.x) * 4;
    unsigned cum = 0;
    #pragma unroll
    for (int j = 0; j < 10; j++){
        unsigned c = counts[j];
        if (e < (size_t)cum + c){
            unsigned off = (unsigned)(e - cum);
            float4 f = *(const float4*)(a.src[j] + off);
            uint2 o;
            o.x = pack2(f.x, f.y);
            o.y = pack2(f.z, f.w);
            *(uint2*)(a.dst[j] + off) = o;
            return;
        }
        cum += c;
    }
}

// ============================================================================
extern "C" void kernel_launch(void* const* d_in, const int* in_sizes, int n_in,
                              void* d_out, int out_size, void* d_ws, size_t ws_size,
                              hipStream_t stream)
{
    const float* hs   = (const float*)d_in[0];   // (16,1024,1280)
    const float* enc  = (const float*)d_in[1];   // (16,477,2048)
    const float* wq   = (const float*)d_in[2];
    const float* wk   = (const float*)d_in[3];
    const float* wv   = (const float*)d_in[4];
    const float* wkb  = (const float*)d_in[5];
    const float* wvb  = (const float*)d_in[6];
    const float* wkc  = (const float*)d_in[7];
    const float* wvc  = (const float*)d_in[8];
    const float* wout = (const float*)d_in[9];
    const float* bout = (const float*)d_in[10];
    float* out = (float*)d_out;

    char* ws = (char*)d_ws;
    size_t off = 0;
    auto alloc = [&](size_t elems) -> unsigned short* {
        unsigned short* p = (unsigned short*)(ws + off);
        off = (off + elems * 2 + 255) & ~(size_t)255;
        return p;
    };
    // adjacent k/v weight pairs form stacked (2560, 2048) weights for fused
    // k|v GEMMs (sizes are multiples of 128 elems -> no alloc padding)
    unsigned short* wq_b   = alloc(1638400);
    unsigned short* wk_b   = alloc(2621440);
    unsigned short* wv_b   = alloc(2621440);
    unsigned short* wkb_b  = alloc(2621440);
    unsigned short* wvb_b  = alloc(2621440);
    unsigned short* wkc_b  = alloc(2621440);
    unsigned short* wvc_b  = alloc(2621440);
    unsigned short* wout_b = alloc(1638400);
    unsigned short* hs_b   = alloc((size_t)BB_ * QQ_ * CC_);
    unsigned short* enc_b  = alloc((size_t)BB_ * LFULL * CROSS);
    unsigned short* q_proj = alloc((size_t)BB_ * QQ_ * CC_);
    unsigned short* kv     = alloc((size_t)BB_ * EHSL * 2560);
    unsigned short* box_kv = alloc((size_t)BB_ * NTOK * 2560);
    unsigned short* cls_kv = alloc((size_t)BB_ * NTOK * 2560);
    unsigned short* out_main = alloc((size_t)BB_ * QQ_ * CC_);

    // 1) fp32 -> bf16
    Cvt10 ca;
    ca.src[0] = wq;   ca.dst[0] = wq_b;
    ca.src[1] = wk;   ca.dst[1] = wk_b;
    ca.src[2] = wv;   ca.dst[2] = wv_b;
    ca.src[3] = wkb;  ca.dst[3] = wkb_b;
    ca.src[4] = wvb;  ca.dst[4] = wvb_b;
    ca.src[5] = wkc;  ca.dst[5] = wkc_b;
    ca.src[6] = wvc;  ca.dst[6] = wvc_b;
    ca.src[7] = wout; ca.dst[7] = wout_b;
    ca.src[8] = hs;   ca.dst[8] = hs_b;
    ca.src[9] = enc;  ca.dst[9] = enc_b;
    hipLaunchKernelGGL(cvt10_kernel, dim3(54304), dim3(256), 0, stream, ca);

    // 2) projections (encoder slices per batch: ehs [0,77), box [77,277), cls [277,477))
    hipLaunchKernelGGL((gemm128<unsigned short>), dim3(20, 10), dim3(256), 0, stream,
                       enc_b,             wk_b,  (const float*)nullptr, kv,
                       BB_*EHSL, 2560, CROSS, EHSL, LFULL);
    hipLaunchKernelGGL((gemm128<unsigned short>), dim3(20, 25), dim3(256), 0, stream,
                       enc_b + 77*CROSS,  wkb_b, (const float*)nullptr, box_kv,
                       BB_*NTOK, 2560, CROSS, NTOK, LFULL);
    hipLaunchKernelGGL((gemm128<unsigned short>), dim3(20, 25), dim3(256), 0, stream,
                       enc_b + 277*CROSS, wkc_b, (const float*)nullptr, cls_kv,
                       BB_*NTOK, 2560, CROSS, NTOK, LFULL);
    hipLaunchKernelGGL((gemm128<unsigned short>), dim3(10, 128), dim3(256), 0, stream,
                       hs_b,              wq_b,  (const float*)nullptr, q_proj,
                       BB_*QQ_, CC_, CC_, BB_*QQ_, 0);

    auto attn_lds = [](int Lk) -> size_t {
        int l16r = (Lk + 15) & ~15;
        int n32  = (Lk + 31) >> 5;
        int vp   = n32 * 32 + 8;
        return (size_t)(l16r * 72 + 64 * vp + 4 * 16 * 40) * 2;
    };

    // 3) cls self-attention (in place on box_kv halves)
    hipLaunchKernelGGL(mattn, dim3(BB_*HEADS, 4), dim3(256), attn_lds(NTOK), stream,
                       box_kv, 2560, 0,    cls_kv, 2560, 1280,
                       box_kv, box_kv, 2560, 0, NTOK, NTOK);
    hipLaunchKernelGGL(mattn, dim3(BB_*HEADS, 4), dim3(256), attn_lds(NTOK), stream,
                       box_kv, 2560, 1280, cls_kv, 2560, 1280,
                       box_kv, box_kv, 2560, 1280, NTOK, NTOK);

    // 4) main attention: out_main = MEA(q, k, v)
    hipLaunchKernelGGL(mattn, dim3(BB_*HEADS, 16), dim3(256), attn_lds(EHSL), stream,
                       q_proj, CC_, 0, kv, 2560, 1280,
                       (const unsigned short*)nullptr, out_main, CC_, 0, QQ_, EHSL);

    // 5) box attention: out_main += MEA(q, box_k', box_v')
    hipLaunchKernelGGL(mattn, dim3(BB_*HEADS, 16), dim3(256), attn_lds(NTOK), stream,
                       q_proj, CC_, 0, box_kv, 2560, 1280,
                       out_main, out_main, CC_, 0, QQ_, NTOK);

    // 6) output projection: out = out_main @ w_out^T + b_out (fp32)
    hipLaunchKernelGGL((gemm128<float>), dim3(10, 128), dim3(256), 0, stream,
                       out_main, wout_b, bout, out, BB_*QQ_, CC_, CC_, BB_*QQ_, 0);
}

// Round 3
// 830.232 us; speedup vs baseline: 1.2377x; 1.2377x over previous
//
#include <hip/hip_runtime.h>
#include <hip/hip_bf16.h>

// ---- problem constants ----
#define BB_   16
#define QQ_   1024
#define CC_   1280
#define LFULL 477
#define CROSS 2048
#define NTOK  200
#define HEADS 20
#define HD    64
#define EHSL  77      // 477 - 200 - 200
#define SCALE_ 0.125f  // 1/sqrt(64)

typedef short bf16x8 __attribute__((ext_vector_type(8)));
typedef float f32x4  __attribute__((ext_vector_type(4)));

__device__ __forceinline__ unsigned short f2bf(float f){
    unsigned u = __float_as_uint(f);
    return (unsigned short)((u + 0x7fffu + ((u >> 16) & 1u)) >> 16);
}
__device__ __forceinline__ unsigned pack2(float a, float b){
    return (unsigned)f2bf(a) | ((unsigned)f2bf(b) << 16);
}
__device__ __forceinline__ float bfu(unsigned short u){
    return __uint_as_float(((unsigned)u) << 16);
}

__device__ __forceinline__ void store_out(unsigned short* p, float v){ *p = f2bf(v); }
__device__ __forceinline__ void store_out(float* p, float v){ *p = v; }

// async global->LDS 16B copy (dest = wave-uniform base + lane*16)
typedef __attribute__((address_space(3))) char lds_char_t;
typedef __attribute__((address_space(1))) char glb_char_t;
__device__ __forceinline__ void async16(const void* g, void* l){
    __builtin_amdgcn_global_load_lds((const glb_char_t*)g, (lds_char_t*)l, 16, 0, 0);
}

// ============================================================================
// 128x128-tile GEMM, 2-phase depth-1 pipeline + COALESCED staging.
//
// Staging: flat index f = r*256+tid maps to row = f>>3 (tile row), c = f&7
// (16B chunk within the row's 128B K-slab). Consecutive lanes cover
// consecutive chunks of the same row => one wave reads 8 full cache lines
// (8 segments/instr) instead of 64 scattered 16B gathers (64 segments).
// LDS is row-major [128][64] (linear dest, as global_load_lds requires).
//
// Bank-conflict fix (T2, both-sides-or-neither, rule #21): source chunk is
// pre-permuted ch = c ^ (row&7) (same cache line => coalescing preserved);
// so LDS[row][c] = G[row][c^(row&7)], and the fragment ds_read fetches
// chunk ch at slot ch^(row&7) (same involution). Read spreads 64 lanes
// uniformly 8-per-bank = the ds_read_b128 floor (conflict-free).
//
// T1: bijective XCD block remap (m204). Double-buffered LDS; next tile's
// global_load_lds issued BEFORE compute; raw s_barrier + explicit vmcnt(0)
// (no implicit drain). sched_barrier(0) pins MFMAs before the barrier.
// C[m][n] = sum_k A[m][k]*W[n][k] (+bias); A,W bf16 row-major K-inner.
// 256 threads = 4 waves, each 64x64 via 4x4 mfma_f32_16x16x32_bf16, BK=64.
// A-row mapping phys = (m/rpb)*bstride + m%rpb handles the encoder slices.
// ============================================================================
template<typename OT>
__global__ __launch_bounds__(256) void gemm128(
    const unsigned short* __restrict__ A,
    const unsigned short* __restrict__ W,
    const float* __restrict__ bias,
    OT* __restrict__ C,
    int M, int N, int K, int rpb, int bstride)
{
    __shared__ unsigned short sA[2][8192];   // 2 x 16 KB, row-major [128][64]
    __shared__ unsigned short sB[2][8192];

    const int tid  = threadIdx.x;
    const int lane = tid & 63;
    const int wave = tid >> 6;
    const int quad = lane >> 4;
    const int l16  = lane & 15;
    const int wm   = wave >> 1;
    const int wn   = wave & 1;

    // T1: XCD-aware bijective remap (m204 formula; safe for nwg % 8 != 0)
    int flat = blockIdx.y * gridDim.x + blockIdx.x;
    {
        const int nwg = (int)(gridDim.x * gridDim.y);
        const int q = nwg >> 3, r = nwg & 7;
        const int xcd = flat & 7, idx = flat >> 3;
        flat = (xcd < r ? xcd * (q + 1) : r * (q + 1) + (xcd - r) * q) + idx;
    }
    const int tm = (flat / (int)gridDim.x) * 128;
    const int tn = (flat % (int)gridDim.x) * 128;

    // staging source pointers: f = r*256+tid -> row = f>>3, chunk = f&7,
    // source chunk pre-swizzled by row&7 (T2 write side)
    const unsigned short* pA[4];
    const unsigned short* pB[4];
    #pragma unroll
    for (int r = 0; r < 4; r++){
        int f   = r * 256 + tid;
        int row = f >> 3;
        int ch  = (f & 7) ^ (row & 7);
        int gm = tm + row; if (gm > M - 1) gm = M - 1;
        int bb = gm / rpb, rr = gm - bb * rpb;
        pA[r] = A + ((size_t)bb * bstride + rr) * (size_t)K + ch * 8;
        pB[r] = W + (size_t)(tn + row) * K + ch * 8;
    }

    f32x4 acc[4][4];
    #pragma unroll
    for (int i = 0; i < 4; i++)
        #pragma unroll
        for (int j = 0; j < 4; j++)
            acc[i][j] = (f32x4){0.f, 0.f, 0.f, 0.f};

    // prologue: stage tile 0 into buffer 0, drain, barrier
    #pragma unroll
    for (int r = 0; r < 4; r++){
        async16(pA[r], (char*)&sA[0][0] + (r * 256 + wave * 64) * 16);
        async16(pB[r], (char*)&sB[0][0] + (r * 256 + wave * 64) * 16);
        pA[r] += 64;
        pB[r] += 64;
    }
    asm volatile("s_waitcnt vmcnt(0)" ::: "memory");
    __builtin_amdgcn_s_barrier();

    int cur = 0;
    for (int k0 = 0; k0 < K; k0 += 64){
        // issue next tile's loads FIRST (they stay in flight across compute)
        if (k0 + 64 < K){
            #pragma unroll
            for (int r = 0; r < 4; r++){
                async16(pA[r], (char*)&sA[cur ^ 1][0] + (r * 256 + wave * 64) * 16);
                async16(pB[r], (char*)&sB[cur ^ 1][0] + (r * 256 + wave * 64) * 16);
                pA[r] += 64;
                pB[r] += 64;
            }
        }

        const unsigned short* cA = &sA[cur][0];
        const unsigned short* cB = &sB[cur][0];
        #pragma unroll
        for (int ks = 0; ks < 2; ks++){
            bf16x8 af[4], bv[4];
            #pragma unroll
            for (int s = 0; s < 4; s++){
                // row-major [row][64] + chunk XOR (T2 read side); data is
                // bit-identical to the old [kg][row][8] fragments
                const int arow = wm*64 + s*16 + l16;
                const int brow = wn*64 + s*16 + l16;
                const int ch   = ks*4 + quad;
                af[s] = *(const bf16x8*)(cA + arow*64 + ((ch ^ (arow & 7)) * 8));
                bv[s] = *(const bf16x8*)(cB + brow*64 + ((ch ^ (brow & 7)) * 8));
            }
            #pragma unroll
            for (int i = 0; i < 4; i++)
                #pragma unroll
                for (int j = 0; j < 4; j++)
                    acc[i][j] = __builtin_amdgcn_mfma_f32_16x16x32_bf16(af[i], bv[j], acc[i][j], 0, 0, 0);
        }

        // pin compute before the barrier, wait for next tile's loads,
        // then raw barrier (no implicit drain of anything else)
        __builtin_amdgcn_sched_barrier(0);
        asm volatile("s_waitcnt vmcnt(0)" ::: "memory");
        __builtin_amdgcn_s_barrier();
        cur ^= 1;
    }

    #pragma unroll
    for (int i = 0; i < 4; i++){
        const int r0 = tm + wm*64 + i*16 + quad*4;
        #pragma unroll
        for (int j = 0; j < 4; j++){
            const int col = tn + wn*64 + j*16 + l16;
            const float bs = bias ? bias[col] : 0.f;
            #pragma unroll
            for (int r = 0; r < 4; r++){
                const int row = r0 + r;
                if (row < M) store_out(C + (size_t)row * N + col, acc[i][j][r] + bs);
            }
        }
    }
}

// ============================================================================
// MFMA flash attention. Block = 4 waves; each wave owns 16 q-rows (block: 64).
// Per (b,h): stage K (pitch 72) and V^T (pitch vp = nk32*32+8, both give
// 2-way-only bank aliasing) in LDS. Per k32 chunk:
//   S-tiles (2x): mfma(Q-frag, K-rows-as-B) -> C-layout S[q=quad*4+r][k=l16];
//   exp + (kpos<Lk) mask -> P bf16 to wave-private LDS (16x40, A-layout);
//   PV: A=P-frag, B=V^T rows (ds_read_b128); ones-column MFMA accumulates the
//   softmax denominator l for free (no max-subtract: scores are O(1), clamp 80).
// Epilogue: broadcast l from l16==0 lanes via ds_swizzle(0x10), scale, +Add,
// scalar bf16 stores. In-place safe: Q read before staging barrier; each block
// writes only its own q-rows.
// ============================================================================
__global__ __launch_bounds__(256) void mattn(
    const unsigned short* __restrict__ Q,  int qstride, int qcoff,
    const unsigned short* __restrict__ KV, int kvstride, int vcoff,
    const unsigned short* __restrict__ Add,              // may be null
    unsigned short* __restrict__ O,   int ostride, int ocoff,
    int qrows, int Lk)
{
    extern __shared__ __align__(16) unsigned short smem[];
    const int Lkc16 = (Lk + 15) & ~15;
    const int nk32  = (Lk + 31) >> 5;
    const int vp    = nk32 * 32 + 8;

    const int tid  = threadIdx.x;
    const int lane = tid & 63;
    const int wave = tid >> 6;
    const int quad = lane >> 4;
    const int l16  = lane & 15;

    unsigned short* sK  = smem;
    unsigned short* sVT = smem + Lkc16 * 72;
    unsigned short* sP  = sVT + 64 * vp + wave * 640;   // 16 x 40 per wave

    const int b = blockIdx.x / HEADS;
    const int h = blockIdx.x % HEADS;
    const int q0 = blockIdx.y * 64 + wave * 16;

    // Q fragments (A-operand: m=l16, k=quad*8+j), loaded before the barrier
    const int qr = min(q0 + l16, qrows - 1);
    const unsigned short* qp = Q + (size_t)(b * qrows + qr) * qstride + h * HD + qcoff;
    bf16x8 qa0 = *(const bf16x8*)(qp + quad * 8);
    bf16x8 qa1 = *(const bf16x8*)(qp + 32 + quad * 8);

    // stage K rows [0, Lkc16), source row clamped
    for (int t = tid; t < Lkc16 * 8; t += 256){
        int row = t >> 3, c = t & 7;
        int sr = min(row, Lk - 1);
        uint4 val = *(const uint4*)(KV + (size_t)(b * Lk + sr) * kvstride + h * HD + c * 8);
        *(uint4*)(sK + row * 72 + c * 8) = val;
    }
    // stage V transposed: V^T[d][kpos], kpos in [0, nk32*32)
    for (int t = tid; t < nk32 * 32 * 8; t += 256){
        int kp_ = t >> 3, c = t & 7;
        int sr = min(kp_, Lk - 1);
        uint4 val = *(const uint4*)(KV + (size_t)(b * Lk + sr) * kvstride + h * HD + vcoff + c * 8);
        unsigned short* col = sVT + (c * 8) * vp + kp_;
        col[0*vp] = (unsigned short)(val.x & 0xffff);
        col[1*vp] = (unsigned short)(val.x >> 16);
        col[2*vp] = (unsigned short)(val.y & 0xffff);
        col[3*vp] = (unsigned short)(val.y >> 16);
        col[4*vp] = (unsigned short)(val.z & 0xffff);
        col[5*vp] = (unsigned short)(val.z >> 16);
        col[6*vp] = (unsigned short)(val.w & 0xffff);
        col[7*vp] = (unsigned short)(val.w >> 16);
    }
    __syncthreads();

    // ones B-fragment: column n==0 of the l-tile
    union { unsigned short us[8]; bf16x8 v; } onesu;
    {
        unsigned short ov = (l16 == 0) ? (unsigned short)0x3f80 : (unsigned short)0;
        #pragma unroll
        for (int i = 0; i < 8; i++) onesu.us[i] = ov;
    }

    f32x4 oacc[4], lacc;
    #pragma unroll
    for (int i = 0; i < 4; i++) oacc[i] = (f32x4){0.f, 0.f, 0.f, 0.f};
    lacc = (f32x4){0.f, 0.f, 0.f, 0.f};

    for (int kb = 0; kb < nk32; kb++){
        #pragma unroll
        for (int st = 0; st < 2; st++){
            const int kt = kb * 32 + st * 16;
            const int krow = min(kt + l16, Lkc16 - 1);
            const unsigned short* kp = sK + krow * 72 + quad * 8;
            bf16x8 k0 = *(const bf16x8*)(kp);
            bf16x8 k1 = *(const bf16x8*)(kp + 32);
            f32x4 s = (f32x4){0.f, 0.f, 0.f, 0.f};
            s = __builtin_amdgcn_mfma_f32_16x16x32_bf16(qa0, k0, s, 0, 0, 0);
            s = __builtin_amdgcn_mfma_f32_16x16x32_bf16(qa1, k1, s, 0, 0, 0);
            const bool valid = (kt + l16) < Lk;
            #pragma unroll
            for (int r = 0; r < 4; r++){
                float sv = fminf(s[r] * SCALE_, 80.f);
                float w = valid ? __expf(sv) : 0.f;
                sP[(quad * 4 + r) * 40 + st * 16 + l16] = f2bf(w);
            }
        }
        // P fragment (A-operand) — wave-private buffer, lgkmcnt ordering only
        bf16x8 pf = *(const bf16x8*)(sP + l16 * 40 + quad * 8);
        lacc = __builtin_amdgcn_mfma_f32_16x16x32_bf16(pf, onesu.v, lacc, 0, 0, 0);
        #pragma unroll
        for (int dt = 0; dt < 4; dt++){
            bf16x8 vb = *(const bf16x8*)(sVT + (dt * 16 + l16) * vp + kb * 32 + quad * 8);
            oacc[dt] = __builtin_amdgcn_mfma_f32_16x16x32_bf16(pf, vb, oacc[dt], 0, 0, 0);
        }
    }

    // epilogue: broadcast l within each quad from l16==0, normalize, add, store
    #pragma unroll
    for (int r = 0; r < 4; r++){
        int li = __builtin_amdgcn_ds_swizzle(__float_as_int(lacc[r]), 0x0010);
        float inv = __builtin_amdgcn_rcpf(__int_as_float(li));
        const int qrow = q0 + quad * 4 + r;
        if (qrow < qrows){
            const size_t og = (size_t)(b * qrows + qrow) * ostride + h * HD + ocoff;
            #pragma unroll
            for (int dt = 0; dt < 4; dt++){
                float v = oacc[dt][r] * inv;
                if (Add) v += bfu(Add[og + dt * 16 + l16]);
                O[og + dt * 16 + l16] = f2bf(v);
            }
        }
    }
}

// ============================================================================
// fp32 -> bf16 conversion, 10 tensors fused (8 weights + hs + enc).
// ============================================================================
struct Cvt10 { const float* src[10]; unsigned short* dst[10]; };

__global__ __launch_bounds__(256) void cvt10_kernel(Cvt10 a)
{
    const unsigned counts[10] = {1638400u, 2621440u, 2621440u, 2621440u,
                                 2621440u, 2621440u, 2621440u, 1638400u,
                                 20971520u, 15630336u};
    size_t e = ((size_t)blockIdx.x * 256 + threadIdx.x) * 4;
    unsigned cum = 0;
    #pragma unroll
    for (int j = 0; j < 10; j++){
        unsigned c = counts[j];
        if (e < (size_t)cum + c){
            unsigned off = (unsigned)(e - cum);
            float4 f = *(const float4*)(a.src[j] + off);
            uint2 o;
            o.x = pack2(f.x, f.y);
            o.y = pack2(f.z, f.w);
            *(uint2*)(a.dst[j] + off) = o;
            return;
        }
        cum += c;
    }
}

// ============================================================================
extern "C" void kernel_launch(void* const* d_in, const int* in_sizes, int n_in,
                              void* d_out, int out_size, void* d_ws, size_t ws_size,
                              hipStream_t stream)
{
    const float* hs   = (const float*)d_in[0];   // (16,1024,1280)
    const float* enc  = (const float*)d_in[1];   // (16,477,2048)
    const float* wq   = (const float*)d_in[2];
    const float* wk   = (const float*)d_in[3];
    const float* wv   = (const float*)d_in[4];
    const float* wkb  = (const float*)d_in[5];
    const float* wvb  = (const float*)d_in[6];
    const float* wkc  = (const float*)d_in[7];
    const float* wvc  = (const float*)d_in[8];
    const float* wout = (const float*)d_in[9];
    const float* bout = (const float*)d_in[10];
    float* out = (float*)d_out;

    char* ws = (char*)d_ws;
    size_t off = 0;
    auto alloc = [&](size_t elems) -> unsigned short* {
        unsigned short* p = (unsigned short*)(ws + off);
        off = (off + elems * 2 + 255) & ~(size_t)255;
        return p;
    };
    // adjacent k/v weight pairs form stacked (2560, 2048) weights for fused
    // k|v GEMMs (sizes are multiples of 128 elems -> no alloc padding)
    unsigned short* wq_b   = alloc(1638400);
    unsigned short* wk_b   = alloc(2621440);
    unsigned short* wv_b   = alloc(2621440);
    unsigned short* wkb_b  = alloc(2621440);
    unsigned short* wvb_b  = alloc(2621440);
    unsigned short* wkc_b  = alloc(2621440);
    unsigned short* wvc_b  = alloc(2621440);
    unsigned short* wout_b = alloc(1638400);
    unsigned short* hs_b   = alloc((size_t)BB_ * QQ_ * CC_);
    unsigned short* enc_b  = alloc((size_t)BB_ * LFULL * CROSS);
    unsigned short* q_proj = alloc((size_t)BB_ * QQ_ * CC_);
    unsigned short* kv     = alloc((size_t)BB_ * EHSL * 2560);
    unsigned short* box_kv = alloc((size_t)BB_ * NTOK * 2560);
    unsigned short* cls_kv = alloc((size_t)BB_ * NTOK * 2560);
    unsigned short* out_main = alloc((size_t)BB_ * QQ_ * CC_);

    // 1) fp32 -> bf16
    Cvt10 ca;
    ca.src[0] = wq;   ca.dst[0] = wq_b;
    ca.src[1] = wk;   ca.dst[1] = wk_b;
    ca.src[2] = wv;   ca.dst[2] = wv_b;
    ca.src[3] = wkb;  ca.dst[3] = wkb_b;
    ca.src[4] = wvb;  ca.dst[4] = wvb_b;
    ca.src[5] = wkc;  ca.dst[5] = wkc_b;
    ca.src[6] = wvc;  ca.dst[6] = wvc_b;
    ca.src[7] = wout; ca.dst[7] = wout_b;
    ca.src[8] = hs;   ca.dst[8] = hs_b;
    ca.src[9] = enc;  ca.dst[9] = enc_b;
    hipLaunchKernelGGL(cvt10_kernel, dim3(54304), dim3(256), 0, stream, ca);

    // 2) projections (encoder slices per batch: ehs [0,77), box [77,277), cls [277,477))
    hipLaunchKernelGGL((gemm128<unsigned short>), dim3(20, 10), dim3(256), 0, stream,
                       enc_b,             wk_b,  (const float*)nullptr, kv,
                       BB_*EHSL, 2560, CROSS, EHSL, LFULL);
    hipLaunchKernelGGL((gemm128<unsigned short>), dim3(20, 25), dim3(256), 0, stream,
                       enc_b + 77*CROSS,  wkb_b, (const float*)nullptr, box_kv,
                       BB_*NTOK, 2560, CROSS, NTOK, LFULL);
    hipLaunchKernelGGL((gemm128<unsigned short>), dim3(20, 25), dim3(256), 0, stream,
                       enc_b + 277*CROSS, wkc_b, (const float*)nullptr, cls_kv,
                       BB_*NTOK, 2560, CROSS, NTOK, LFULL);
    hipLaunchKernelGGL((gemm128<unsigned short>), dim3(10, 128), dim3(256), 0, stream,
                       hs_b,              wq_b,  (const float*)nullptr, q_proj,
                       BB_*QQ_, CC_, CC_, BB_*QQ_, 0);

    auto attn_lds = [](int Lk) -> size_t {
        int l16r = (Lk + 15) & ~15;
        int n32  = (Lk + 31) >> 5;
        int vp   = n32 * 32 + 8;
        return (size_t)(l16r * 72 + 64 * vp + 4 * 16 * 40) * 2;
    };

    // 3) cls self-attention (in place on box_kv halves)
    hipLaunchKernelGGL(mattn, dim3(BB_*HEADS, 4), dim3(256), attn_lds(NTOK), stream,
                       box_kv, 2560, 0,    cls_kv, 2560, 1280,
                       box_kv, box_kv, 2560, 0, NTOK, NTOK);
    hipLaunchKernelGGL(mattn, dim3(BB_*HEADS, 4), dim3(256), attn_lds(NTOK), stream,
                       box_kv, 2560, 1280, cls_kv, 2560, 1280,
                       box_kv, box_kv, 2560, 1280, NTOK, NTOK);

    // 4) main attention: out_main = MEA(q, k, v)
    hipLaunchKernelGGL(mattn, dim3(BB_*HEADS, 16), dim3(256), attn_lds(EHSL), stream,
                       q_proj, CC_, 0, kv, 2560, 1280,
                       (const unsigned short*)nullptr, out_main, CC_, 0, QQ_, EHSL);

    // 5) box attention: out_main += MEA(q, box_k', box_v')
    hipLaunchKernelGGL(mattn, dim3(BB_*HEADS, 16), dim3(256), attn_lds(NTOK), stream,
                       q_proj, CC_, 0, box_kv, 2560, 1280,
                       out_main, out_main, CC_, 0, QQ_, NTOK);

    // 6) output projection: out = out_main @ w_out^T + b_out (fp32)
    hipLaunchKernelGGL((gemm128<float>), dim3(10, 128), dim3(256), 0, stream,
                       out_main, wout_b, bout, out, BB_*QQ_, CC_, CC_, BB_*QQ_, 0);
}

// Round 5
// 792.308 us; speedup vs baseline: 1.2970x; 1.0479x over previous
//
#include <hip/hip_runtime.h>
#include <hip/hip_bf16.h>

// ---- problem constants ----
#define BB_   16
#define QQ_   1024
#define CC_   1280
#define LFULL 477
#define CROSS 2048
#define NTOK  200
#define HEADS 20
#define HD    64
#define EHSL  77      // 477 - 200 - 200
#define SCALE_ 0.125f  // 1/sqrt(64)

typedef short bf16x8 __attribute__((ext_vector_type(8)));
typedef float f32x4  __attribute__((ext_vector_type(4)));

__device__ __forceinline__ unsigned short f2bf(float f){
    unsigned u = __float_as_uint(f);
    return (unsigned short)((u + 0x7fffu + ((u >> 16) & 1u)) >> 16);
}
__device__ __forceinline__ unsigned pack2(float a, float b){
    return (unsigned)f2bf(a) | ((unsigned)f2bf(b) << 16);
}
__device__ __forceinline__ float bfu(unsigned short u){
    return __uint_as_float(((unsigned)u) << 16);
}

__device__ __forceinline__ void store_out(unsigned short* p, float v){ *p = f2bf(v); }
__device__ __forceinline__ void store_out(float* p, float v){ *p = v; }

// async global->LDS 16B copy (dest = wave-uniform base + lane*16)
typedef __attribute__((address_space(3))) char lds_char_t;
typedef __attribute__((address_space(1))) char glb_char_t;
__device__ __forceinline__ void async16(const void* g, void* l){
    __builtin_amdgcn_global_load_lds((const glb_char_t*)g, (lds_char_t*)l, 16, 0, 0);
}

// ============================================================================
// 128x128-tile GEMM, 2-phase depth-1 pipeline + COALESCED staging.
// (unchanged from round 3 — verified: gemm128 dropped below attn in profile)
// ============================================================================
template<typename OT>
__global__ __launch_bounds__(256) void gemm128(
    const unsigned short* __restrict__ A,
    const unsigned short* __restrict__ W,
    const float* __restrict__ bias,
    OT* __restrict__ C,
    int M, int N, int K, int rpb, int bstride)
{
    __shared__ unsigned short sA[2][8192];   // 2 x 16 KB, row-major [128][64]
    __shared__ unsigned short sB[2][8192];

    const int tid  = threadIdx.x;
    const int lane = tid & 63;
    const int wave = tid >> 6;
    const int quad = lane >> 4;
    const int l16  = lane & 15;
    const int wm   = wave >> 1;
    const int wn   = wave & 1;

    // T1: XCD-aware bijective remap (m204 formula; safe for nwg % 8 != 0)
    int flat = blockIdx.y * gridDim.x + blockIdx.x;
    {
        const int nwg = (int)(gridDim.x * gridDim.y);
        const int q = nwg >> 3, r = nwg & 7;
        const int xcd = flat & 7, idx = flat >> 3;
        flat = (xcd < r ? xcd * (q + 1) : r * (q + 1) + (xcd - r) * q) + idx;
    }
    const int tm = (flat / (int)gridDim.x) * 128;
    const int tn = (flat % (int)gridDim.x) * 128;

    // staging: f = r*256+tid -> row = f>>3, chunk c = f&7; source chunk
    // pre-swizzled c^(row&7) (T2 write side, same cache line)
    const unsigned short* pA[4];
    const unsigned short* pB[4];
    #pragma unroll
    for (int r = 0; r < 4; r++){
        int f   = r * 256 + tid;
        int row = f >> 3;
        int ch  = (f & 7) ^ (row & 7);
        int gm = tm + row; if (gm > M - 1) gm = M - 1;
        int bb = gm / rpb, rr = gm - bb * rpb;
        pA[r] = A + ((size_t)bb * bstride + rr) * (size_t)K + ch * 8;
        pB[r] = W + (size_t)(tn + row) * K + ch * 8;
    }

    f32x4 acc[4][4];
    #pragma unroll
    for (int i = 0; i < 4; i++)
        #pragma unroll
        for (int j = 0; j < 4; j++)
            acc[i][j] = (f32x4){0.f, 0.f, 0.f, 0.f};

    // prologue: stage tile 0 into buffer 0, drain, barrier
    #pragma unroll
    for (int r = 0; r < 4; r++){
        async16(pA[r], (char*)&sA[0][0] + (r * 256 + wave * 64) * 16);
        async16(pB[r], (char*)&sB[0][0] + (r * 256 + wave * 64) * 16);
        pA[r] += 64;
        pB[r] += 64;
    }
    asm volatile("s_waitcnt vmcnt(0)" ::: "memory");
    __builtin_amdgcn_s_barrier();

    int cur = 0;
    for (int k0 = 0; k0 < K; k0 += 64){
        if (k0 + 64 < K){
            #pragma unroll
            for (int r = 0; r < 4; r++){
                async16(pA[r], (char*)&sA[cur ^ 1][0] + (r * 256 + wave * 64) * 16);
                async16(pB[r], (char*)&sB[cur ^ 1][0] + (r * 256 + wave * 64) * 16);
                pA[r] += 64;
                pB[r] += 64;
            }
        }

        const unsigned short* cA = &sA[cur][0];
        const unsigned short* cB = &sB[cur][0];
        #pragma unroll
        for (int ks = 0; ks < 2; ks++){
            bf16x8 af[4], bv[4];
            #pragma unroll
            for (int s = 0; s < 4; s++){
                const int arow = wm*64 + s*16 + l16;
                const int brow = wn*64 + s*16 + l16;
                const int ch   = ks*4 + quad;
                af[s] = *(const bf16x8*)(cA + arow*64 + ((ch ^ (arow & 7)) * 8));
                bv[s] = *(const bf16x8*)(cB + brow*64 + ((ch ^ (brow & 7)) * 8));
            }
            #pragma unroll
            for (int i = 0; i < 4; i++)
                #pragma unroll
                for (int j = 0; j < 4; j++)
                    acc[i][j] = __builtin_amdgcn_mfma_f32_16x16x32_bf16(af[i], bv[j], acc[i][j], 0, 0, 0);
        }

        __builtin_amdgcn_sched_barrier(0);
        asm volatile("s_waitcnt vmcnt(0)" ::: "memory");
        __builtin_amdgcn_s_barrier();
        cur ^= 1;
    }

    #pragma unroll
    for (int i = 0; i < 4; i++){
        const int r0 = tm + wm*64 + i*16 + quad*4;
        #pragma unroll
        for (int j = 0; j < 4; j++){
            const int col = tn + wn*64 + j*16 + l16;
            const float bs = bias ? bias[col] : 0.f;
            #pragma unroll
            for (int r = 0; r < 4; r++){
                const int row = r0 + r;
                if (row < M) store_out(C + (size_t)row * N + col, acc[i][j][r] + bs);
            }
        }
    }
}

// ============================================================================
// MFMA flash attention (round-3 verified structure + two staging fixes).
// Block = 4 waves; each wave owns 16 q-rows per q-tile; nqb q-tiles/block
// (K/V staged ONCE per (b,h) block, amortized over nqb tiles).
//
// V^T layout with XOR swizzle (both-sides involution, rule #21):
//   elem (kp, d) at short addr d*vp + ((kp>>3 ^ d>>3) << 3) + (kp&7),
//   vp = 8*cap + 8, cap = roundup8(4*nk32)  (XOR range fits: kpb^c < cap).
//   Write scatter: per store i, lanes' bank blocks = (kpb ^ c) spread over all
//   8 block positions (c = d>>3 is the lane's chunk id) -> conflict-free
//   (was 8-way: 4*c*vp = 0 mod 32 for any vp in 8Z).
//   Read (b128, 8 consecutive kp at block kb*4+quad): same XOR with row>>3;
//   block idx (l16 + (kpb_r ^ (dt*2 + (l16>>3)))) mod 8 -> uniform 8
//   lanes/4-dword block = b128 floor. k-order unchanged vs round 3.
//
// Per k32 chunk: S-tiles (2x): mfma(Q, K-rows) -> S[q=quad*4+r][k=l16];
// exp + mask -> P bf16 to wave-private LDS (16x40, A-layout); PV: A=P-frag,
// B=V^T rows; ones-column MFMA accumulates denominator l (no max-subtract:
// scores O(1), clamp 80). Epilogue: broadcast l via ds_swizzle(0x10),
// normalize, +Add, store. In-place safe: each (qi,wave) pair owns disjoint
// q-rows (qi*4+wave unique), reads its Q/Add rows before writing them, and
// K/V staging completes before any O write.
// ============================================================================
__global__ __launch_bounds__(256) void mattn(
    const unsigned short* __restrict__ Q,  int qstride, int qcoff,
    const unsigned short* __restrict__ KV, int kvstride, int vcoff,
    const unsigned short* __restrict__ Add,              // may be null
    unsigned short* __restrict__ O,   int ostride, int ocoff,
    int qrows, int Lk, int nqb)
{
    extern __shared__ __align__(16) unsigned short smem[];
    const int Lkc16 = (Lk + 15) & ~15;
    const int nk32  = (Lk + 31) >> 5;
    const int cap   = ((nk32 * 4 - 1) | 7) + 1;
    const int vp    = cap * 8 + 8;

    const int tid  = threadIdx.x;
    const int lane = tid & 63;
    const int wave = tid >> 6;
    const int quad = lane >> 4;
    const int l16  = lane & 15;

    unsigned short* sK  = smem;                     // Lkc16 x 72
    unsigned short* sVT = smem + Lkc16 * 72;        // 64 x vp (XOR-swizzled)
    unsigned short* sP  = sVT + 64 * vp + wave * 640;   // 16 x 40 per wave

    const int b = blockIdx.x / HEADS;
    const int h = blockIdx.x % HEADS;

    // stage K rows [0, Lkc16), source row clamped (pitch 72: conflict-free)
    for (int t = tid; t < Lkc16 * 8; t += 256){
        int row = t >> 3, c = t & 7;
        int sr = min(row, Lk - 1);
        uint4 val = *(const uint4*)(KV + (size_t)(b * Lk + sr) * kvstride + h * HD + c * 8);
        *(uint4*)(sK + row * 72 + c * 8) = val;
    }
    // stage V transposed with XOR swizzle: rows d = c*8+i all share d>>3 = c
    for (int t = tid; t < nk32 * 32 * 8; t += 256){
        int kp_ = t >> 3, c = t & 7;
        int sr = min(kp_, Lk - 1);
        uint4 val = *(const uint4*)(KV + (size_t)(b * Lk + sr) * kvstride + h * HD + vcoff + c * 8);
        unsigned short* col = sVT + (c * 8) * vp + (((kp_ >> 3) ^ c) << 3) + (kp_ & 7);
        col[0*vp] = (unsigned short)(val.x & 0xffff);
        col[1*vp] = (unsigned short)(val.x >> 16);
        col[2*vp] = (unsigned short)(val.y & 0xffff);
        col[3*vp] = (unsigned short)(val.y >> 16);
        col[4*vp] = (unsigned short)(val.z & 0xffff);
        col[5*vp] = (unsigned short)(val.z >> 16);
        col[6*vp] = (unsigned short)(val.w & 0xffff);
        col[7*vp] = (unsigned short)(val.w >> 16);
    }
    __syncthreads();

    // ones B-fragment: column n==0 of the l-tile
    union { unsigned short us[8]; bf16x8 v; } onesu;
    {
        unsigned short ov = (l16 == 0) ? (unsigned short)0x3f80 : (unsigned short)0;
        #pragma unroll
        for (int i = 0; i < 8; i++) onesu.us[i] = ov;
    }

    for (int qi = 0; qi < nqb; qi++){
        const int q0 = (blockIdx.y * nqb + qi) * 64 + wave * 16;

        // Q fragments (A-operand: m=l16, k=quad*8+j)
        const int qr = min(q0 + l16, qrows - 1);
        const unsigned short* qp = Q + (size_t)(b * qrows + qr) * qstride + h * HD + qcoff;
        bf16x8 qa0 = *(const bf16x8*)(qp + quad * 8);
        bf16x8 qa1 = *(const bf16x8*)(qp + 32 + quad * 8);

        f32x4 oacc[4], lacc;
        #pragma unroll
        for (int i = 0; i < 4; i++) oacc[i] = (f32x4){0.f, 0.f, 0.f, 0.f};
        lacc = (f32x4){0.f, 0.f, 0.f, 0.f};

        for (int kb = 0; kb < nk32; kb++){
            #pragma unroll
            for (int st = 0; st < 2; st++){
                const int kt = kb * 32 + st * 16;
                const int krow = min(kt + l16, Lkc16 - 1);
                const unsigned short* kp = sK + krow * 72 + quad * 8;
                bf16x8 k0 = *(const bf16x8*)(kp);
                bf16x8 k1 = *(const bf16x8*)(kp + 32);
                f32x4 s = (f32x4){0.f, 0.f, 0.f, 0.f};
                s = __builtin_amdgcn_mfma_f32_16x16x32_bf16(qa0, k0, s, 0, 0, 0);
                s = __builtin_amdgcn_mfma_f32_16x16x32_bf16(qa1, k1, s, 0, 0, 0);
                const bool valid = (kt + l16) < Lk;
                #pragma unroll
                for (int r = 0; r < 4; r++){
                    float sv = fminf(s[r] * SCALE_, 80.f);
                    float w = valid ? __expf(sv) : 0.f;
                    sP[(quad * 4 + r) * 40 + st * 16 + l16] = f2bf(w);
                }
            }
            // P fragment (A-operand) — wave-private buffer, lgkmcnt ordering only
            bf16x8 pf = *(const bf16x8*)(sP + l16 * 40 + quad * 8);
            lacc = __builtin_amdgcn_mfma_f32_16x16x32_bf16(pf, onesu.v, lacc, 0, 0, 0);
            #pragma unroll
            for (int dt = 0; dt < 4; dt++){
                const int row = dt * 16 + l16;
                bf16x8 vb = *(const bf16x8*)(sVT + row * vp
                              + ((((kb << 2) + quad) ^ (row >> 3)) << 3));
                oacc[dt] = __builtin_amdgcn_mfma_f32_16x16x32_bf16(pf, vb, oacc[dt], 0, 0, 0);
            }
        }

        // epilogue: broadcast l within each quad from l16==0, normalize, add, store
        #pragma unroll
        for (int r = 0; r < 4; r++){
            int li = __builtin_amdgcn_ds_swizzle(__float_as_int(lacc[r]), 0x0010);
            float inv = __builtin_amdgcn_rcpf(__int_as_float(li));
            const int qrow = q0 + quad * 4 + r;
            if (qrow < qrows){
                const size_t og = (size_t)(b * qrows + qrow) * ostride + h * HD + ocoff;
                #pragma unroll
                for (int dt = 0; dt < 4; dt++){
                    float v = oacc[dt][r] * inv;
                    if (Add) v += bfu(Add[og + dt * 16 + l16]);
                    O[og + dt * 16 + l16] = f2bf(v);
                }
            }
        }
    }
}

// ============================================================================
// fp32 -> bf16 conversion, 10 tensors fused (8 weights + hs + enc).
// ============================================================================
struct Cvt10 { const float* src[10]; unsigned short* dst[10]; };

__global__ __launch_bounds__(256) void cvt10_kernel(Cvt10 a)
{
    const unsigned counts[10] = {1638400u, 2621440u, 2621440u, 2621440u,
                                 2621440u, 2621440u, 2621440u, 1638400u,
                                 20971520u, 15630336u};
    size_t e = ((size_t)blockIdx.x * 256 + threadIdx.x) * 4;
    unsigned cum = 0;
    #pragma unroll
    for (int j = 0; j < 10; j++){
        unsigned c = counts[j];
        if (e < (size_t)cum + c){
            unsigned off = (unsigned)(e - cum);
            float4 f = *(const float4*)(a.src[j] + off);
            uint2 o;
            o.x = pack2(f.x, f.y);
            o.y = pack2(f.z, f.w);
            *(uint2*)(a.dst[j] + off) = o;
            return;
        }
        cum += c;
    }
}

// ============================================================================
extern "C" void kernel_launch(void* const* d_in, const int* in_sizes, int n_in,
                              void* d_out, int out_size, void* d_ws, size_t ws_size,
                              hipStream_t stream)
{
    const float* hs   = (const float*)d_in[0];   // (16,1024,1280)
    const float* enc  = (const float*)d_in[1];   // (16,477,2048)
    const float* wq   = (const float*)d_in[2];
    const float* wk   = (const float*)d_in[3];
    const float* wv   = (const float*)d_in[4];
    const float* wkb  = (const float*)d_in[5];
    const float* wvb  = (const float*)d_in[6];
    const float* wkc  = (const float*)d_in[7];
    const float* wvc  = (const float*)d_in[8];
    const float* wout = (const float*)d_in[9];
    const float* bout = (const float*)d_in[10];
    float* out = (float*)d_out;

    char* ws = (char*)d_ws;
    size_t off = 0;
    auto alloc = [&](size_t elems) -> unsigned short* {
        unsigned short* p = (unsigned short*)(ws + off);
        off = (off + elems * 2 + 255) & ~(size_t)255;
        return p;
    };
    // adjacent k/v weight pairs form stacked (2560, 2048) weights for fused
    // k|v GEMMs (sizes are multiples of 128 elems -> no alloc padding)
    unsigned short* wq_b   = alloc(1638400);
    unsigned short* wk_b   = alloc(2621440);
    unsigned short* wv_b   = alloc(2621440);
    unsigned short* wkb_b  = alloc(2621440);
    unsigned short* wvb_b  = alloc(2621440);
    unsigned short* wkc_b  = alloc(2621440);
    unsigned short* wvc_b  = alloc(2621440);
    unsigned short* wout_b = alloc(1638400);
    unsigned short* hs_b   = alloc((size_t)BB_ * QQ_ * CC_);
    unsigned short* enc_b  = alloc((size_t)BB_ * LFULL * CROSS);
    unsigned short* q_proj = alloc((size_t)BB_ * QQ_ * CC_);
    unsigned short* kv     = alloc((size_t)BB_ * EHSL * 2560);
    unsigned short* box_kv = alloc((size_t)BB_ * NTOK * 2560);
    unsigned short* cls_kv = alloc((size_t)BB_ * NTOK * 2560);
    unsigned short* out_main = alloc((size_t)BB_ * QQ_ * CC_);

    // 1) fp32 -> bf16
    Cvt10 ca;
    ca.src[0] = wq;   ca.dst[0] = wq_b;
    ca.src[1] = wk;   ca.dst[1] = wk_b;
    ca.src[2] = wv;   ca.dst[2] = wv_b;
    ca.src[3] = wkb;  ca.dst[3] = wkb_b;
    ca.src[4] = wvb;  ca.dst[4] = wvb_b;
    ca.src[5] = wkc;  ca.dst[5] = wkc_b;
    ca.src[6] = wvc;  ca.dst[6] = wvc_b;
    ca.src[7] = wout; ca.dst[7] = wout_b;
    ca.src[8] = hs;   ca.dst[8] = hs_b;
    ca.src[9] = enc;  ca.dst[9] = enc_b;
    hipLaunchKernelGGL(cvt10_kernel, dim3(54304), dim3(256), 0, stream, ca);

    // 2) projections (encoder slices per batch: ehs [0,77), box [77,277), cls [277,477))
    hipLaunchKernelGGL((gemm128<unsigned short>), dim3(20, 10), dim3(256), 0, stream,
                       enc_b,             wk_b,  (const float*)nullptr, kv,
                       BB_*EHSL, 2560, CROSS, EHSL, LFULL);
    hipLaunchKernelGGL((gemm128<unsigned short>), dim3(20, 25), dim3(256), 0, stream,
                       enc_b + 77*CROSS,  wkb_b, (const float*)nullptr, box_kv,
                       BB_*NTOK, 2560, CROSS, NTOK, LFULL);
    hipLaunchKernelGGL((gemm128<unsigned short>), dim3(20, 25), dim3(256), 0, stream,
                       enc_b + 277*CROSS, wkc_b, (const float*)nullptr, cls_kv,
                       BB_*NTOK, 2560, CROSS, NTOK, LFULL);
    hipLaunchKernelGGL((gemm128<unsigned short>), dim3(10, 128), dim3(256), 0, stream,
                       hs_b,              wq_b,  (const float*)nullptr, q_proj,
                       BB_*QQ_, CC_, CC_, BB_*QQ_, 0);

    auto attn_lds = [](int Lk) -> size_t {
        int l16r = (Lk + 15) & ~15;
        int n32  = (Lk + 31) >> 5;
        int cap  = ((n32 * 4 - 1) | 7) + 1;
        int vp   = cap * 8 + 8;
        return (size_t)(l16r * 72 + 64 * vp + 4 * 16 * 40) * 2;
    };

    // 3) cls self-attention (in place on box_kv halves)
    hipLaunchKernelGGL(mattn, dim3(BB_*HEADS, 4), dim3(256), attn_lds(NTOK), stream,
                       box_kv, 2560, 0,    cls_kv, 2560, 1280,
                       box_kv, box_kv, 2560, 0, NTOK, NTOK, 1);
    hipLaunchKernelGGL(mattn, dim3(BB_*HEADS, 4), dim3(256), attn_lds(NTOK), stream,
                       box_kv, 2560, 1280, cls_kv, 2560, 1280,
                       box_kv, box_kv, 2560, 1280, NTOK, NTOK, 1);

    // 4) main attention: out_main = MEA(q, k, v)  (4 q-tiles per block)
    hipLaunchKernelGGL(mattn, dim3(BB_*HEADS, 4), dim3(256), attn_lds(EHSL), stream,
                       q_proj, CC_, 0, kv, 2560, 1280,
                       (const unsigned short*)nullptr, out_main, CC_, 0, QQ_, EHSL, 4);

    // 5) box attention: out_main += MEA(q, box_k', box_v')  (4 q-tiles per block)
    hipLaunchKernelGGL(mattn, dim3(BB_*HEADS, 4), dim3(256), attn_lds(NTOK), stream,
                       q_proj, CC_, 0, box_kv, 2560, 1280,
                       out_main, out_main, CC_, 0, QQ_, NTOK, 4);

    // 6) output projection: out = out_main @ w_out^T + b_out (fp32)
    hipLaunchKernelGGL((gemm128<float>), dim3(10, 128), dim3(256), 0, stream,
                       out_main, wout_b, bout, out, BB_*QQ_, CC_, CC_, BB_*QQ_, 0);
}